// Round 4
// baseline (847.030 us; speedup 1.0000x reference)
//
#include <hip/hip_runtime.h>

#define LRC 0.01f
#define LSEQ 4096
#define HIDDIM 128

typedef float f32x2 __attribute__((ext_vector_type(2)));
typedef unsigned int u32x2 __attribute__((ext_vector_type(2)));

#define PKFMA(a, b, c) __builtin_elementwise_fma((a), (b), (c))
static __device__ __forceinline__ f32x2 splat2(float s) {
  f32x2 r; r.x = s; r.y = s; return r;
}

// Fused DPP add: x += dpp_move(x, CTRL), 0-fill for invalid lanes.
#define DPP_ADD(x, ctrl)                                                     \
  x += __int_as_float(__builtin_amdgcn_update_dpp(                           \
      0, __float_as_int(x), (ctrl), 0xf, 0xf, true))

// Classic 64-lane sum -> wave-uniform scalar (used for the lone kk value).
__device__ __forceinline__ float red64(float x) {
  DPP_ADD(x, 0x111);  // row_shr:1
  DPP_ADD(x, 0x112);  // row_shr:2
  DPP_ADD(x, 0x114);  // row_shr:4
  DPP_ADD(x, 0x118);  // row_shr:8
  DPP_ADD(x, 0x142);  // row_bcast:15
  DPP_ADD(x, 0x143);  // row_bcast:31
  return __int_as_float(__builtin_amdgcn_readlane(__float_as_int(x), 63));
}

// 4 simultaneous 64-lane sums in 14 instrs:
// permlane32_swap folds 64->32 for two values at once,
// permlane16_swap folds 32->16 for all four,
// 4 shared row_shr stages, readlane 15/31/47/63.
__device__ __forceinline__ void quad_red(float p, float q, float u, float w,
                                         float& rp, float& rq, float& ru,
                                         float& rw) {
  u32x2 s1 = __builtin_amdgcn_permlane32_swap(__float_as_uint(p),
                                              __float_as_uint(q), false, false);
  float zpq = __uint_as_float(s1.x) + __uint_as_float(s1.y);
  u32x2 s2 = __builtin_amdgcn_permlane32_swap(__float_as_uint(u),
                                              __float_as_uint(w), false, false);
  float zuw = __uint_as_float(s2.x) + __uint_as_float(s2.y);
  u32x2 s3 = __builtin_amdgcn_permlane16_swap(__float_as_uint(zpq),
                                              __float_as_uint(zuw), false, false);
  float y = __uint_as_float(s3.x) + __uint_as_float(s3.y);
  DPP_ADD(y, 0x111);
  DPP_ADD(y, 0x112);
  DPP_ADD(y, 0x114);
  DPP_ADD(y, 0x118);
  rp = __int_as_float(__builtin_amdgcn_readlane(__float_as_int(y), 15));
  ru = __int_as_float(__builtin_amdgcn_readlane(__float_as_int(y), 31));
  rq = __int_as_float(__builtin_amdgcn_readlane(__float_as_int(y), 47));
  rw = __int_as_float(__builtin_amdgcn_readlane(__float_as_int(y), 63));
}

__global__ __launch_bounds__(64) void ttt_kernel(
    const float* __restrict__ h, const float* __restrict__ W1,
    const float* __restrict__ b1, const float* __restrict__ W2,
    const float* __restrict__ b2, float* __restrict__ out) {
  const int b = blockIdx.x;
  const int lane = threadIdx.x;  // 0..63
  const int d0 = lane * 2;       // lane owns hidden dims d0, d0+1
  const float* __restrict__ hb = h + (size_t)b * (LSEQ * HIDDIM);

  // ---- weight state in registers (d-indexed values packed as f32x2) ----
  f32x2 w1v[8];  // (W1[i][d0], W1[i][d0+1])
  f32x2 w2v[8];  // (W2[d0][i], W2[d0+1][i])
  float b1r[8];  // replicated (wave-uniform)
#pragma unroll
  for (int i = 0; i < 8; ++i) {
    w1v[i] = *reinterpret_cast<const f32x2*>(W1 + i * HIDDIM + d0);
    w2v[i].x = W2[(size_t)d0 * 8 + i];
    w2v[i].y = W2[(size_t)(d0 + 1) * 8 + i];
    b1r[i] = b1[i];
  }
  f32x2 b2v = *reinterpret_cast<const f32x2*>(b2 + d0);

  const float cneg = -(LRC * 2.0f / (float)HIDDIM);
  const f32x2 cnegv = {cneg, cneg};

  // ---- 3-slot k/v rotation, prefetch distance 3 steps ----
  const float* pf = hb + d0;
  f32x2 kA = *reinterpret_cast<const f32x2*>(pf + 0 * HIDDIM);
  f32x2 vA = *reinterpret_cast<const f32x2*>(pf + 1 * HIDDIM);
  f32x2 kB = *reinterpret_cast<const f32x2*>(pf + 2 * HIDDIM);
  f32x2 vB = *reinterpret_cast<const f32x2*>(pf + 3 * HIDDIM);
  f32x2 kC = *reinterpret_cast<const f32x2*>(pf + 4 * HIDDIM);
  f32x2 vC = *reinterpret_cast<const f32x2*>(pf + 5 * HIDDIM);
  pf += 6 * HIDDIM;

  // ---- a(0) = W1 k(0) + b1 ----
  float aIn[8];
  {
    float pa[8];
#pragma unroll
    for (int i = 0; i < 8; ++i) pa[i] = fmaf(w1v[i].x, kA.x, w1v[i].y * kA.y);
    float t0, t1, t2, t3, t4, t5, t6, t7;
    quad_red(pa[0], pa[1], pa[2], pa[3], t0, t1, t2, t3);
    quad_red(pa[4], pa[5], pa[6], pa[7], t4, t5, t6, t7);
    aIn[0] = t0 + b1r[0]; aIn[1] = t1 + b1r[1];
    aIn[2] = t2 + b1r[2]; aIn[3] = t3 + b1r[3];
    aIn[4] = t4 + b1r[4]; aIn[5] = t5 + b1r[5];
    aIn[6] = t6 + b1r[6]; aIn[7] = t7 + b1r[7];
  }

  // One SGD step s. In: a(s) (aIn, uniform), k(s), v(s), k(s+1).
  // Out: updated weights, aIn = a(s+1) via rank-1 factorization:
  //   a(s+1) = red(W1(s) k(s+1)) + da(s)*(red(k(s)·k(s+1)) + 1) + b1(s)
  auto STEP = [&](f32x2 k, f32x2 v, f32x2 kn) {
    // relu (uniform scalars)
    float r_[8];
#pragma unroll
    for (int i = 0; i < 8; ++i) r_[i] = fmaxf(aIn[i], 0.0f);
    // pred = W2 r + b2 : packed, two partial accumulators
    f32x2 p0 = PKFMA(w2v[0], splat2(r_[0]), b2v);
    f32x2 p1 = w2v[1] * splat2(r_[1]);
#pragma unroll
    for (int i = 2; i < 8; i += 2) {
      p0 = PKFMA(w2v[i], splat2(r_[i]), p0);
      p1 = PKFMA(w2v[i + 1], splat2(r_[i + 1]), p1);
    }
    f32x2 gl = ((p0 + p1) - v) * cnegv;
    // da partials from OLD w2 (horizontal dot over the lane's 2 dims)
    float dp[8];
#pragma unroll
    for (int i = 0; i < 8; ++i) dp[i] = fmaf(w2v[i].x, gl.x, w2v[i].y * gl.y);
    float dr0, dr1, dr2, dr3, dr4, dr5, dr6, dr7;
    quad_red(dp[0], dp[1], dp[2], dp[3], dr0, dr1, dr2, dr3);
    quad_red(dp[4], dp[5], dp[6], dp[7], dr4, dr5, dr6, dr7);
    float dpred[8] = {dr0, dr1, dr2, dr3, dr4, dr5, dr6, dr7};
    // next-step a partials with OLD w1 and k(s+1); kk = k(s)·k(s+1)
    float tp[8];
#pragma unroll
    for (int i = 0; i < 8; ++i) tp[i] = fmaf(w1v[i].x, kn.x, w1v[i].y * kn.y);
    float kkp = fmaf(k.x, kn.x, k.y * kn.y);
    float u0, u1, u2, u3, u4, u5, u6, u7;
    quad_red(tp[0], tp[1], tp[2], tp[3], u0, u1, u2, u3);
    quad_red(tp[4], tp[5], tp[6], tp[7], u4, u5, u6, u7);
    float t1r[8] = {u0, u1, u2, u3, u4, u5, u6, u7};
    float kkp1 = red64(kkp) + 1.0f;
    // w2 / b2 update (packed)
#pragma unroll
    for (int i = 0; i < 8; ++i) w2v[i] = PKFMA(gl, splat2(r_[i]), w2v[i]);
    b2v += gl;
    // mask (uniform -> SALU select), w1 / b1 update, next a
#pragma unroll
    for (int i = 0; i < 8; ++i) {
      // aIn[i] is wave-uniform: ballot is all-ones or zero -> scalar select
      unsigned long long m = __ballot(aIn[i] > 0.0f);
      float da = m ? dpred[i] : 0.0f;            // == -lr * da_ref, in SGPR
      float tb = t1r[i] + b1r[i];                // uses OLD b1
      w1v[i] = PKFMA(splat2(da), k, w1v[i]);
      b1r[i] += da;
      aIn[i] = fmaf(da, kkp1, tb);               // a(s+1)
    }
  };

  // steps 0..2042: 681 iterations x 3 (3-slot rotation)
  for (int it = 0; it < 681; ++it) {
    {
      f32x2 k = kA, v = vA, kn = kB;
      kA = *reinterpret_cast<const f32x2*>(pf + 0 * HIDDIM);
      vA = *reinterpret_cast<const f32x2*>(pf + 1 * HIDDIM);
      STEP(k, v, kn);  // s = 3it
    }
    {
      f32x2 k = kB, v = vB, kn = kC;
      kB = *reinterpret_cast<const f32x2*>(pf + 2 * HIDDIM);
      vB = *reinterpret_cast<const f32x2*>(pf + 3 * HIDDIM);
      STEP(k, v, kn);  // s = 3it+1
    }
    {
      f32x2 k = kC, v = vC, kn = kA;  // kn = freshly loaded k(3it+3)
      kC = *reinterpret_cast<const f32x2*>(pf + 4 * HIDDIM);
      vC = *reinterpret_cast<const f32x2*>(pf + 5 * HIDDIM);
      STEP(k, v, kn);  // s = 3it+2
    }
    pf += 6 * HIDDIM;
  }

  // tail: pf at row 4092. steps 2043..2046, then final predict with row 4095.
  f32x2 kD = *reinterpret_cast<const f32x2*>(pf + 0 * HIDDIM);  // row 4092
  f32x2 vD = *reinterpret_cast<const f32x2*>(pf + 1 * HIDDIM);  // row 4093
  f32x2 kE = *reinterpret_cast<const f32x2*>(pf + 2 * HIDDIM);  // row 4094
  f32x2 xv = *reinterpret_cast<const f32x2*>(pf + 3 * HIDDIM);  // row 4095
  STEP(kA, vA, kB);  // 2043
  STEP(kB, vB, kC);  // 2044
  STEP(kC, vC, kD);  // 2045
  STEP(kD, vD, kE);  // 2046 (kn only feeds a discarded aIn)

  // ---- final prediction with x = h[b, L-1] ----
  float pa[8];
#pragma unroll
  for (int i = 0; i < 8; ++i) pa[i] = fmaf(w1v[i].x, xv.x, w1v[i].y * xv.y);
  float f0, f1, f2, f3, f4, f5, f6, f7;
  quad_red(pa[0], pa[1], pa[2], pa[3], f0, f1, f2, f3);
  quad_red(pa[4], pa[5], pa[6], pa[7], f4, f5, f6, f7);
  float fr[8] = {f0, f1, f2, f3, f4, f5, f6, f7};
  f32x2 o = b2v;
#pragma unroll
  for (int i = 0; i < 8; ++i) {
    float r = fmaxf(fr[i] + b1r[i], 0.0f);
    o = PKFMA(w2v[i], splat2(r), o);
  }
  *reinterpret_cast<f32x2*>(out + (size_t)b * HIDDIM + d0) = o;
}

extern "C" void kernel_launch(void* const* d_in, const int* in_sizes, int n_in,
                              void* d_out, int out_size, void* d_ws, size_t ws_size,
                              hipStream_t stream) {
  const float* h  = (const float*)d_in[0];
  const float* W1 = (const float*)d_in[1];
  const float* b1 = (const float*)d_in[2];
  const float* W2 = (const float*)d_in[3];
  const float* b2 = (const float*)d_in[4];
  float* out = (float*)d_out;
  ttt_kernel<<<256, 64, 0, stream>>>(h, W1, b1, W2, b2, out);
}

// Round 5
// 699.550 us; speedup vs baseline: 1.2108x; 1.2108x over previous
//
#include <hip/hip_runtime.h>

#define LRC 0.01f
#define LSEQ 4096
#define HIDDIM 128

typedef unsigned int u32x2 __attribute__((ext_vector_type(2)));

// Fused DPP add: x += dpp_move(x, CTRL), 0-fill for invalid lanes.
#define DPP_ADD(x, ctrl)                                                     \
  x += __int_as_float(__builtin_amdgcn_update_dpp(                           \
      0, __float_as_int(x), (ctrl), 0xf, 0xf, true))

// 4 concurrent 64-lane sums, results left IN LANES (no readlane):
// lane15 = sum(p), lane31 = sum(u), lane47 = sum(q), lane63 = sum(w).
// For call (x0,x1,x2,x3): group g=(lane>>4) holds element ((g&1)<<1)|(g>>1).
__device__ __forceinline__ float quad_red_nr(float p, float q, float u, float w) {
  u32x2 s1 = __builtin_amdgcn_permlane32_swap(__float_as_uint(p),
                                              __float_as_uint(q), false, false);
  float zpq = __uint_as_float(s1.x) + __uint_as_float(s1.y);
  u32x2 s2 = __builtin_amdgcn_permlane32_swap(__float_as_uint(u),
                                              __float_as_uint(w), false, false);
  float zuw = __uint_as_float(s2.x) + __uint_as_float(s2.y);
  u32x2 s3 = __builtin_amdgcn_permlane16_swap(__float_as_uint(zpq),
                                              __float_as_uint(zuw), false, false);
  float y = __uint_as_float(s3.x) + __uint_as_float(s3.y);
  DPP_ADD(y, 0x111);
  DPP_ADD(y, 0x112);
  DPP_ADD(y, 0x114);
  DPP_ADD(y, 0x118);
  return y;
}

// 64-lane sum; total lands at lane 63 (no readlane).
__device__ __forceinline__ float red64_nr(float x) {
  DPP_ADD(x, 0x111);
  DPP_ADD(x, 0x112);
  DPP_ADD(x, 0x114);
  DPP_ADD(x, 0x118);
  DPP_ADD(x, 0x142);
  DPP_ADD(x, 0x143);
  return x;
}

// Wave A: serial core (w2/b2/b1, pred, gl, dp-reduce, mask, aIn).
// Wave B: W1 owner (applies da(s-1), computes tp(s)=red(W1(s)*k(s+1)), kk(s)).
// Handoff per step via LDS + one __syncthreads (double-buffered slots).
__global__ __launch_bounds__(128) void ttt_kernel(
    const float* __restrict__ h, const float* __restrict__ W1,
    const float* __restrict__ b1, const float* __restrict__ W2,
    const float* __restrict__ b2, float* __restrict__ out) {
  __shared__ __align__(16) float sm[40];
  const int b = blockIdx.x;
  const int tid = threadIdx.x;
  const int wv = tid >> 6;       // 0 = wave A, 1 = wave B
  const int lane = tid & 63;
  const int d0 = lane * 2;       // lane owns hidden dims d0, d0+1
  const float* __restrict__ hb = h + (size_t)b * (LSEQ * HIDDIM);
  const int g = lane >> 4;
  const int wIdx = ((g & 1) << 1) | (g >> 1);  // reduced-lane elem index

  float* const tp0 = sm;         // floats 0..7   (16B aligned)
  float* const tp1 = sm + 8;     // floats 8..15
  float* const kk0 = sm + 16;
  float* const kk1s = sm + 17;
  float* const da0 = sm + 20;    // floats 20..27 (80B, 16B aligned)
  float* const da1 = sm + 28;    // floats 28..35

  if (wv == 0) {
    // ================= WAVE A =================
    const float cneg = -(LRC * 2.0f / (float)HIDDIM);
    float2 w2v[8];
    float b1u[8];
#pragma unroll
    for (int i = 0; i < 8; ++i) {
      w2v[i].x = W2[(size_t)d0 * 8 + i];
      w2v[i].y = W2[(size_t)(d0 + 1) * 8 + i];
      b1u[i] = b1[i];
    }
    float2 b2v = *reinterpret_cast<const float2*>(b2 + d0);
    float b1V1 = b1[wIdx];       // reduced-lane copies of b1
    float b1V2 = b1[4 + wIdx];
    // v(s) = row 2s+1; 4-slot rotation, prefetch distance ~2 pairs
    float2 vR0 = *(const float2*)(hb + 1 * HIDDIM + d0);
    float2 vR1 = *(const float2*)(hb + 3 * HIDDIM + d0);
    float2 vR2 = *(const float2*)(hb + 5 * HIDDIM + d0);
    float2 vR3 = *(const float2*)(hb + 7 * HIDDIM + d0);

    __syncthreads();  // X_{-1}: B's tpInit ready in tp1

    float aU[8], aV1, aV2;
    {
      float4 ta = *(float4*)tp1;
      float4 tb = *(float4*)(tp1 + 4);
      float tu[8] = {ta.x, ta.y, ta.z, ta.w, tb.x, tb.y, tb.z, tb.w};
#pragma unroll
      for (int i = 0; i < 8; ++i) aU[i] = tu[i] + b1u[i];
      aV1 = tp1[wIdx] + b1V1;
      aV2 = tp1[4 + wIdx] + b1V2;
    }

    auto STEPA = [&](float* tpS, float* kkS, float* daS, float2 vcur) {
      float r0[8];
#pragma unroll
      for (int i = 0; i < 8; ++i) r0[i] = fmaxf(aU[i], 0.0f);
      // pred = W2 r + b2 (two partial accumulators)
      float2 p0, p1;
      p0.x = fmaf(w2v[0].x, r0[0], b2v.x);
      p0.y = fmaf(w2v[0].y, r0[0], b2v.y);
      p1.x = w2v[1].x * r0[1];
      p1.y = w2v[1].y * r0[1];
#pragma unroll
      for (int i = 2; i < 8; i += 2) {
        p0.x = fmaf(w2v[i].x, r0[i], p0.x);
        p0.y = fmaf(w2v[i].y, r0[i], p0.y);
        p1.x = fmaf(w2v[i + 1].x, r0[i + 1], p1.x);
        p1.y = fmaf(w2v[i + 1].y, r0[i + 1], p1.y);
      }
      float2 gl;
      gl.x = (p0.x + p1.x - vcur.x) * cneg;
      gl.y = (p0.y + p1.y - vcur.y) * cneg;
      // da partials from OLD w2
      float dp[8];
#pragma unroll
      for (int i = 0; i < 8; ++i) dp[i] = fmaf(w2v[i].x, gl.x, w2v[i].y * gl.y);
      float y1 = quad_red_nr(dp[0], dp[1], dp[2], dp[3]);
      float y2 = quad_red_nr(dp[4], dp[5], dp[6], dp[7]);
      // mask in reduced-lane layout (aV holds a_i at the resident lanes)
      y1 = (aV1 > 0.0f) ? y1 : 0.0f;
      y2 = (aV2 > 0.0f) ? y2 : 0.0f;
      if ((lane & 15) == 15) {
        daS[wIdx] = y1;
        daS[4 + wIdx] = y2;
      }
      // w2 / b2 update
#pragma unroll
      for (int i = 0; i < 8; ++i) {
        w2v[i].x = fmaf(gl.x, r0[i], w2v[i].x);
        w2v[i].y = fmaf(gl.y, r0[i], w2v[i].y);
      }
      b2v.x += gl.x;
      b2v.y += gl.y;
      __syncthreads();  // X_s : da(s) -> B ; tp(s),kk(s) -> A
      float4 ta = *(float4*)tpS;
      float4 tb = *(float4*)(tpS + 4);
      float4 dqa = *(float4*)daS;
      float4 dqb = *(float4*)(daS + 4);
      float kkp1 = kkS[0] + 1.0f;
      float tV1 = tpS[wIdx], tV2 = tpS[4 + wIdx];
      float dV1 = daS[wIdx], dV2 = daS[4 + wIdx];
      float tu[8] = {ta.x, ta.y, ta.z, ta.w, tb.x, tb.y, tb.z, tb.w};
      float da[8] = {dqa.x, dqa.y, dqa.z, dqa.w, dqb.x, dqb.y, dqb.z, dqb.w};
#pragma unroll
      for (int i = 0; i < 8; ++i) {
        aU[i] = fmaf(da[i], kkp1, tu[i] + b1u[i]);  // a(s+1)
        b1u[i] += da[i];
      }
      aV1 = fmaf(dV1, kkp1, tV1 + b1V1);
      b1V1 += dV1;
      aV2 = fmaf(dV2, kkp1, tV2 + b1V2);
      b1V2 += dV2;
    };

    // pairs s=(2p, 2p+1), p=0..1022 ; then peel s=2046
    for (int p = 0; p < 1023; ++p) {
      int s = 2 * p;
      int ra = 2 * s + 9;   // row of v(s+4)
      int rb = 2 * s + 11;  // row of v(s+5)
      ra = ra > (LSEQ - 1) ? (LSEQ - 1) : ra;
      rb = rb > (LSEQ - 1) ? (LSEQ - 1) : rb;
      float2 t0 = *(const float2*)(hb + (size_t)ra * HIDDIM + d0);
      float2 t1 = *(const float2*)(hb + (size_t)rb * HIDDIM + d0);
      STEPA(tp0, kk0, da0, vR0);   // s even  -> slot 0
      STEPA(tp1, kk1s, da1, vR1);  // s+1 odd -> slot 1
      vR0 = vR2; vR1 = vR3; vR2 = t0; vR3 = t1;
    }
    STEPA(tp0, kk0, da0, vR0);  // s = 2046 (slot 0)

    __syncthreads();  // X_2047 : tp_fin ready in tp1
    {
      float4 ta = *(float4*)tp1;
      float4 tb = *(float4*)(tp1 + 4);
      float tu[8] = {ta.x, ta.y, ta.z, ta.w, tb.x, tb.y, tb.z, tb.w};
      float2 o = b2v;
#pragma unroll
      for (int i = 0; i < 8; ++i) {
        float r = fmaxf(tu[i] + b1u[i], 0.0f);
        o.x = fmaf(w2v[i].x, r, o.x);
        o.y = fmaf(w2v[i].y, r, o.y);
      }
      *reinterpret_cast<float2*>(out + (size_t)b * HIDDIM + d0) = o;
    }
  } else {
    // ================= WAVE B =================
    float2 w1v[8];
#pragma unroll
    for (int i = 0; i < 8; ++i)
      w1v[i] = *(const float2*)(W1 + i * HIDDIM + d0);
    // k(m) = row 2m ; 6-slot rotation
    float2 kR0 = *(const float2*)(hb + 0 * HIDDIM + d0);
    float2 kR1 = *(const float2*)(hb + 2 * HIDDIM + d0);
    float2 kR2 = *(const float2*)(hb + 4 * HIDDIM + d0);
    float2 kR3 = *(const float2*)(hb + 6 * HIDDIM + d0);
    float2 kR4 = *(const float2*)(hb + 8 * HIDDIM + d0);
    float2 kR5 = *(const float2*)(hb + 10 * HIDDIM + d0);
    float2 xv = *(const float2*)(hb + (size_t)(LSEQ - 1) * HIDDIM + d0);

    // tpInit = red(W1(0)*k(0)) -> tp1 (A forms aIn(0) from it)
    {
      float tp[8];
#pragma unroll
      for (int i = 0; i < 8; ++i) tp[i] = fmaf(w1v[i].x, kR0.x, w1v[i].y * kR0.y);
      float y1 = quad_red_nr(tp[0], tp[1], tp[2], tp[3]);
      float y2 = quad_red_nr(tp[4], tp[5], tp[6], tp[7]);
      if ((lane & 15) == 15) {
        tp1[wIdx] = y1;
        tp1[4 + wIdx] = y2;
      }
    }
    __syncthreads();  // X_{-1}

    // peel j=0: no da yet. tp(0)=red(W1(0)*k(1)), kk(0)=k(0)·k(1) -> slot 0
    {
      float tp[8];
#pragma unroll
      for (int i = 0; i < 8; ++i) tp[i] = fmaf(w1v[i].x, kR1.x, w1v[i].y * kR1.y);
      float kkp = fmaf(kR0.x, kR1.x, kR0.y * kR1.y);
      float y1 = quad_red_nr(tp[0], tp[1], tp[2], tp[3]);
      float y2 = quad_red_nr(tp[4], tp[5], tp[6], tp[7]);
      float kkr = red64_nr(kkp);
      if ((lane & 15) == 15) {
        tp0[wIdx] = y1;
        tp0[4 + wIdx] = y2;
      }
      if (lane == 63) kk0[0] = kkr;
    }
    __syncthreads();  // X_0

    auto STEPB = [&](float* daS, float* tpS, float* kkS, float2 km1, float2 kc,
                     float2 kp) {
      // read da(j-1) (masked, broadcast) and apply to W1
      float4 dqa = *(float4*)daS;
      float4 dqb = *(float4*)(daS + 4);
      float da[8] = {dqa.x, dqa.y, dqa.z, dqa.w, dqb.x, dqb.y, dqb.z, dqb.w};
#pragma unroll
      for (int i = 0; i < 8; ++i) {
        w1v[i].x = fmaf(da[i], km1.x, w1v[i].x);
        w1v[i].y = fmaf(da[i], km1.y, w1v[i].y);
      }
      // tp(j) = red(W1(j)*k(j+1)), kk(j) = k(j)·k(j+1)
      float tp[8];
#pragma unroll
      for (int i = 0; i < 8; ++i) tp[i] = fmaf(w1v[i].x, kp.x, w1v[i].y * kp.y);
      float kkp = fmaf(kc.x, kp.x, kc.y * kp.y);
      float y1 = quad_red_nr(tp[0], tp[1], tp[2], tp[3]);
      float y2 = quad_red_nr(tp[4], tp[5], tp[6], tp[7]);
      float kkr = red64_nr(kkp);
      if ((lane & 15) == 15) {
        tpS[wIdx] = y1;
        tpS[4 + wIdx] = y2;
      }
      if (lane == 63) kkS[0] = kkr;
      __syncthreads();  // X_j
    };

    // pairs j=(2p+1, 2p+2), p=0..1022
    for (int p = 0; p < 1023; ++p) {
      int j = 2 * p + 1;
      int ra = 2 * j + 10;  // row of k(j+5)
      int rb = 2 * j + 12;  // row of k(j+6)
      ra = ra > (LSEQ - 1) ? (LSEQ - 1) : ra;
      rb = rb > (LSEQ - 1) ? (LSEQ - 1) : rb;
      float2 t0 = *(const float2*)(hb + (size_t)ra * HIDDIM + d0);
      float2 t1 = *(const float2*)(hb + (size_t)rb * HIDDIM + d0);
      STEPB(da0, tp1, kk1s, kR0, kR1, kR2);  // j odd : da slot 0, write slot 1
      STEPB(da1, tp0, kk0, kR1, kR2, kR3);   // j+1   : da slot 1, write slot 0
      kR0 = kR2; kR1 = kR3; kR2 = kR4; kR3 = kR5; kR4 = t0; kR5 = t1;
    }

    // epilogue j=2047: apply da(2046) w/ k(2046)=kR0; tp_fin = red(W1*x) -> tp1
    {
      float4 dqa = *(float4*)da0;
      float4 dqb = *(float4*)(da0 + 4);
      float da[8] = {dqa.x, dqa.y, dqa.z, dqa.w, dqb.x, dqb.y, dqb.z, dqb.w};
#pragma unroll
      for (int i = 0; i < 8; ++i) {
        w1v[i].x = fmaf(da[i], kR0.x, w1v[i].x);
        w1v[i].y = fmaf(da[i], kR0.y, w1v[i].y);
      }
      float tp[8];
#pragma unroll
      for (int i = 0; i < 8; ++i) tp[i] = fmaf(w1v[i].x, xv.x, w1v[i].y * xv.y);
      float y1 = quad_red_nr(tp[0], tp[1], tp[2], tp[3]);
      float y2 = quad_red_nr(tp[4], tp[5], tp[6], tp[7]);
      if ((lane & 15) == 15) {
        tp1[wIdx] = y1;
        tp1[4 + wIdx] = y2;
      }
    }
    __syncthreads();  // X_2047
  }
}

extern "C" void kernel_launch(void* const* d_in, const int* in_sizes, int n_in,
                              void* d_out, int out_size, void* d_ws, size_t ws_size,
                              hipStream_t stream) {
  const float* h  = (const float*)d_in[0];
  const float* W1 = (const float*)d_in[1];
  const float* b1 = (const float*)d_in[2];
  const float* W2 = (const float*)d_in[3];
  const float* b2 = (const float*)d_in[4];
  float* out = (float*)d_out;
  ttt_kernel<<<256, 128, 0, stream>>>(h, W1, b1, W2, b2, out);
}

// Round 6
// 641.811 us; speedup vs baseline: 1.3197x; 1.0900x over previous
//
#include <hip/hip_runtime.h>

#define LRC 0.01f
#define LSEQ 4096
#define HIDDIM 128

typedef unsigned int u32x2 __attribute__((ext_vector_type(2)));

// x += row_ror(x, N) : after rors {8,4,2,1} every lane holds its 16-row's sum.
#define RORADD(x, ctrl)                                                      \
  x += __int_as_float(__builtin_amdgcn_update_dpp(                           \
      0, __float_as_int(x), (ctrl), 0xf, 0xf, true))

// 4 concurrent 64-lane sums, ALL-LANES result, row-mapped:
// row r (lanes 16r..16r+15) all hold sum(x_{sig(r)}), sig = [0,2,1,3].
__device__ __forceinline__ float allred4(float x0, float x1, float x2,
                                         float x3) {
  u32x2 s1 = __builtin_amdgcn_permlane32_swap(__float_as_uint(x0),
                                              __float_as_uint(x1), false, false);
  float z01 = __uint_as_float(s1.x) + __uint_as_float(s1.y);
  u32x2 s2 = __builtin_amdgcn_permlane32_swap(__float_as_uint(x2),
                                              __float_as_uint(x3), false, false);
  float z23 = __uint_as_float(s2.x) + __uint_as_float(s2.y);
  u32x2 s3 = __builtin_amdgcn_permlane16_swap(__float_as_uint(z01),
                                              __float_as_uint(z23), false, false);
  float y = __uint_as_float(s3.x) + __uint_as_float(s3.y);
  RORADD(y, 0x128);
  RORADD(y, 0x124);
  RORADD(y, 0x122);
  RORADD(y, 0x121);
  return y;
}

// 64-lane sum, result uniform across ALL lanes (no readlane).
__device__ __forceinline__ float allred1(float x) {
  u32x2 s1 = __builtin_amdgcn_permlane32_swap(__float_as_uint(x),
                                              __float_as_uint(x), false, false);
  float z = __uint_as_float(s1.x) + __uint_as_float(s1.y);
  u32x2 s2 = __builtin_amdgcn_permlane16_swap(__float_as_uint(z),
                                              __float_as_uint(z), false, false);
  z = __uint_as_float(s2.x) + __uint_as_float(s2.y);
  RORADD(z, 0x128);
  RORADD(z, 0x124);
  RORADD(z, 0x122);
  RORADD(z, 0x121);
  return z;
}

// Row-mapped reg z (rows = [m0,m1,m2,m3]) -> 4 all-lane-uniform regs.
// For z = allred4(x0,x1,x2,x3), returns (x0, x1, x2, x3) in natural order.
__device__ __forceinline__ void bcast4(float z, float& u0, float& u1,
                                       float& u2, float& u3) {
  u32x2 t = __builtin_amdgcn_permlane16_swap(__float_as_uint(z),
                                             __float_as_uint(z), false, false);
  u32x2 p = __builtin_amdgcn_permlane32_swap(t.x, t.x, false, false);
  u32x2 q = __builtin_amdgcn_permlane32_swap(t.y, t.y, false, false);
  u0 = __uint_as_float(p.x);   // m0
  u1 = __uint_as_float(p.y);   // m2
  u2 = __uint_as_float(q.x);   // m1
  u3 = __uint_as_float(q.y);   // m3
}

// Wave A: serial core (w2/b2/b1, pred, gl, dp-reduce, mask, aIn).
// Wave B: W1 owner (applies da(s-1), computes tp(s)=red(W1(s)k(s+1)), kk(s)).
// Handoff via LDS row-lead writes + one __syncthreads per step (dbuf slots).
__global__ __launch_bounds__(128) void ttt_kernel(
    const float* __restrict__ h, const float* __restrict__ W1,
    const float* __restrict__ b1, const float* __restrict__ W2,
    const float* __restrict__ b2, float* __restrict__ out) {
  // layout (floats): tp0 0..7, kk0 8..11, tp1 12..19, kk1 20..23,
  //                  da0 24..31 (byte 96, 16B aligned), da1 32..39
  __shared__ __align__(16) float sm[40];
  const int b = blockIdx.x;
  const int tid = threadIdx.x;
  const int wv = tid >> 6;  // 0 = wave A, 1 = wave B
  const int lane = tid & 63;
  const int d0 = lane * 2;
  const float* __restrict__ hb = h + (size_t)b * (LSEQ * HIDDIM);
  const int g = lane >> 4;
  const int sig = ((g & 1) << 1) | (g >> 1);  // row r holds inner unit sig(r)
  const bool rowlead = ((lane & 15) == 0);

  float* const tp0 = sm;
  float* const tp1 = sm + 12;
  float* const da0 = sm + 24;
  float* const da1 = sm + 32;

  if (wv == 0) {
    // ================= WAVE A =================
    const float cneg = -(LRC * 2.0f / (float)HIDDIM);
    float2 w2v[8];
#pragma unroll
    for (int i = 0; i < 8; ++i) {
      w2v[i].x = W2[(size_t)d0 * 8 + i];
      w2v[i].y = W2[(size_t)(d0 + 1) * 8 + i];
    }
    float2 b2v = *reinterpret_cast<const float2*>(b2 + d0);
    float b1A = b1[sig];      // row-mapped b1 state
    float b1B = b1[4 + sig];
    // v(s) = row 2s+1; 4-slot rotation
    float2 vR0 = *(const float2*)(hb + 1 * HIDDIM + d0);
    float2 vR1 = *(const float2*)(hb + 3 * HIDDIM + d0);
    float2 vR2 = *(const float2*)(hb + 5 * HIDDIM + d0);
    float2 vR3 = *(const float2*)(hb + 7 * HIDDIM + d0);

    __syncthreads();  // X_{-1}: B's tpInit ready in tp1

    float aA = tp1[sig] + b1A;      // a(0), row-mapped
    float aB = tp1[4 + sig] + b1B;

    auto STEPA = [&](float* tpS, float* daS, float2 vcur) {
      // relu + broadcast r to all lanes
      float rA = fmaxf(aA, 0.0f), rB = fmaxf(aB, 0.0f);
      float r0, r1, r2, r3, r4, r5, r6, r7;
      bcast4(rA, r0, r1, r2, r3);
      bcast4(rB, r4, r5, r6, r7);
      // pred = W2 r + b2 (two partial accumulators)
      float2 p0, p1;
      p0.x = fmaf(w2v[0].x, r0, b2v.x);
      p0.y = fmaf(w2v[0].y, r0, b2v.y);
      p1.x = w2v[1].x * r1;
      p1.y = w2v[1].y * r1;
      p0.x = fmaf(w2v[2].x, r2, p0.x);
      p0.y = fmaf(w2v[2].y, r2, p0.y);
      p1.x = fmaf(w2v[3].x, r3, p1.x);
      p1.y = fmaf(w2v[3].y, r3, p1.y);
      p0.x = fmaf(w2v[4].x, r4, p0.x);
      p0.y = fmaf(w2v[4].y, r4, p0.y);
      p1.x = fmaf(w2v[5].x, r5, p1.x);
      p1.y = fmaf(w2v[5].y, r5, p1.y);
      p0.x = fmaf(w2v[6].x, r6, p0.x);
      p0.y = fmaf(w2v[6].y, r6, p0.y);
      p1.x = fmaf(w2v[7].x, r7, p1.x);
      p1.y = fmaf(w2v[7].y, r7, p1.y);
      float2 gl;
      gl.x = (p0.x + p1.x - vcur.x) * cneg;
      gl.y = (p0.y + p1.y - vcur.y) * cneg;
      // dp partials from OLD w2, batched all-lane reductions (row-mapped out)
      float dp[8];
#pragma unroll
      for (int i = 0; i < 8; ++i) dp[i] = fmaf(w2v[i].x, gl.x, w2v[i].y * gl.y);
      float zA = allred4(dp[0], dp[1], dp[2], dp[3]);
      float zB = allred4(dp[4], dp[5], dp[6], dp[7]);
      // mask by a>0 (row-mapped, aligned layouts)
      float daA = (aA > 0.0f) ? zA : 0.0f;
      float daB = (aB > 0.0f) ? zB : 0.0f;
      if (rowlead) {
        daS[sig] = daA;
        daS[4 + sig] = daB;
      }
      __syncthreads();  // X_s : da(s) -> B ; tp(s), kk(s) -> A
      // issue tp/kk reads, hide latency under w2/b2 update
      float tA = tpS[sig];
      float tB = tpS[4 + sig];
      float kk = tpS[8];
#pragma unroll
      for (int i = 0; i < 8; ++i) {
        float ri;
        if (i == 0) ri = r0; else if (i == 1) ri = r1; else if (i == 2) ri = r2;
        else if (i == 3) ri = r3; else if (i == 4) ri = r4; else if (i == 5) ri = r5;
        else if (i == 6) ri = r6; else ri = r7;
        w2v[i].x = fmaf(gl.x, ri, w2v[i].x);
        w2v[i].y = fmaf(gl.y, ri, w2v[i].y);
      }
      b2v.x += gl.x;
      b2v.y += gl.y;
      float kkp1 = kk + 1.0f;
      aA = fmaf(daA, kkp1, tA + b1A);  // a(s+1), uses OLD b1
      aB = fmaf(daB, kkp1, tB + b1B);
      b1A += daA;
      b1B += daB;
    };

    // pairs s=(2p, 2p+1), p=0..1022 ; then peel s=2046
    for (int p = 0; p < 1023; ++p) {
      int s = 2 * p;
      int ra = 2 * s + 9;   // row of v(s+4)
      int rb = 2 * s + 11;  // row of v(s+5)
      ra = ra > (LSEQ - 1) ? (LSEQ - 1) : ra;
      rb = rb > (LSEQ - 1) ? (LSEQ - 1) : rb;
      float2 t0 = *(const float2*)(hb + (size_t)ra * HIDDIM + d0);
      float2 t1 = *(const float2*)(hb + (size_t)rb * HIDDIM + d0);
      STEPA(tp0, da0, vR0);  // s even  -> slot 0
      STEPA(tp1, da1, vR1);  // s+1 odd -> slot 1
      vR0 = vR2; vR1 = vR3; vR2 = t0; vR3 = t1;
    }
    STEPA(tp0, da0, vR0);  // s = 2046 (slot 0)

    __syncthreads();  // X_2047 : tp_fin in tp1
    {
      float aAf = fmaxf(tp1[sig] + b1A, 0.0f);
      float aBf = fmaxf(tp1[4 + sig] + b1B, 0.0f);
      float r0, r1, r2, r3, r4, r5, r6, r7;
      bcast4(aAf, r0, r1, r2, r3);
      bcast4(aBf, r4, r5, r6, r7);
      float2 o = b2v;
      o.x = fmaf(w2v[0].x, r0, o.x); o.y = fmaf(w2v[0].y, r0, o.y);
      o.x = fmaf(w2v[1].x, r1, o.x); o.y = fmaf(w2v[1].y, r1, o.y);
      o.x = fmaf(w2v[2].x, r2, o.x); o.y = fmaf(w2v[2].y, r2, o.y);
      o.x = fmaf(w2v[3].x, r3, o.x); o.y = fmaf(w2v[3].y, r3, o.y);
      o.x = fmaf(w2v[4].x, r4, o.x); o.y = fmaf(w2v[4].y, r4, o.y);
      o.x = fmaf(w2v[5].x, r5, o.x); o.y = fmaf(w2v[5].y, r5, o.y);
      o.x = fmaf(w2v[6].x, r6, o.x); o.y = fmaf(w2v[6].y, r6, o.y);
      o.x = fmaf(w2v[7].x, r7, o.x); o.y = fmaf(w2v[7].y, r7, o.y);
      *reinterpret_cast<float2*>(out + (size_t)b * HIDDIM + d0) = o;
    }
  } else {
    // ================= WAVE B =================
    float2 w1v[8];
#pragma unroll
    for (int i = 0; i < 8; ++i)
      w1v[i] = *(const float2*)(W1 + i * HIDDIM + d0);
    // k(m) = row 2m ; 6-slot rotation
    float2 kR0 = *(const float2*)(hb + 0 * HIDDIM + d0);
    float2 kR1 = *(const float2*)(hb + 2 * HIDDIM + d0);
    float2 kR2 = *(const float2*)(hb + 4 * HIDDIM + d0);
    float2 kR3 = *(const float2*)(hb + 6 * HIDDIM + d0);
    float2 kR4 = *(const float2*)(hb + 8 * HIDDIM + d0);
    float2 kR5 = *(const float2*)(hb + 10 * HIDDIM + d0);
    float2 xv = *(const float2*)(hb + (size_t)(LSEQ - 1) * HIDDIM + d0);

    // tpInit = red(W1(0)k(0)) -> tp1
    {
      float tp[8];
#pragma unroll
      for (int i = 0; i < 8; ++i) tp[i] = fmaf(w1v[i].x, kR0.x, w1v[i].y * kR0.y);
      float zA = allred4(tp[0], tp[1], tp[2], tp[3]);
      float zB = allred4(tp[4], tp[5], tp[6], tp[7]);
      if (rowlead) {
        tp1[sig] = zA;
        tp1[4 + sig] = zB;
      }
    }
    __syncthreads();  // X_{-1}

    // peel j=0: no da. tp(0)=red(W1(0)k(1)), kk(0)=k(0)·k(1) -> slot 0
    {
      float tp[8];
#pragma unroll
      for (int i = 0; i < 8; ++i) tp[i] = fmaf(w1v[i].x, kR1.x, w1v[i].y * kR1.y);
      float zA = allred4(tp[0], tp[1], tp[2], tp[3]);
      float zB = allred4(tp[4], tp[5], tp[6], tp[7]);
      float kku = allred1(fmaf(kR0.x, kR1.x, kR0.y * kR1.y));
      if (rowlead) {
        tp0[sig] = zA;
        tp0[4 + sig] = zB;
        tp0[8 + g] = kku;  // 4 copies, distinct addrs; A reads [8]
      }
    }
    __syncthreads();  // X_0

    auto STEPB = [&](float* daS, float* tpS, float2 km1, float2 kc, float2 kp) {
      // read da(j-1) (uniform float4s) and apply to W1
      float4 dq0 = *(float4*)daS;
      float4 dq1 = *(float4*)(daS + 4);
      float da[8] = {dq0.x, dq0.y, dq0.z, dq0.w, dq1.x, dq1.y, dq1.z, dq1.w};
#pragma unroll
      for (int i = 0; i < 8; ++i) {
        w1v[i].x = fmaf(da[i], km1.x, w1v[i].x);
        w1v[i].y = fmaf(da[i], km1.y, w1v[i].y);
      }
      // tp(j) = red(W1(j)k(j+1)), kk(j) = k(j)·k(j+1)
      float tp[8];
#pragma unroll
      for (int i = 0; i < 8; ++i) tp[i] = fmaf(w1v[i].x, kp.x, w1v[i].y * kp.y);
      float zA = allred4(tp[0], tp[1], tp[2], tp[3]);
      float zB = allred4(tp[4], tp[5], tp[6], tp[7]);
      float kku = allred1(fmaf(kc.x, kp.x, kc.y * kp.y));
      if (rowlead) {
        tpS[sig] = zA;
        tpS[4 + sig] = zB;
        tpS[8 + g] = kku;
      }
      __syncthreads();  // X_j
    };

    // pairs j=(2p+1, 2p+2), p=0..1022
    for (int p = 0; p < 1023; ++p) {
      int j = 2 * p + 1;
      int ra = 2 * j + 10;  // row of k(j+5)
      int rb = 2 * j + 12;  // row of k(j+6)
      ra = ra > (LSEQ - 1) ? (LSEQ - 1) : ra;
      rb = rb > (LSEQ - 1) ? (LSEQ - 1) : rb;
      float2 t0 = *(const float2*)(hb + (size_t)ra * HIDDIM + d0);
      float2 t1 = *(const float2*)(hb + (size_t)rb * HIDDIM + d0);
      STEPB(da0, tp1, kR0, kR1, kR2);  // j odd : da slot 0, write slot 1
      STEPB(da1, tp0, kR1, kR2, kR3);  // j+1   : da slot 1, write slot 0
      kR0 = kR2; kR1 = kR3; kR2 = kR4; kR3 = kR5; kR4 = t0; kR5 = t1;
    }

    // epilogue j=2047: apply da(2046) w/ k(2046)=kR0; tp_fin=red(W1 x) -> tp1
    {
      float4 dq0 = *(float4*)da0;
      float4 dq1 = *(float4*)(da0 + 4);
      float da[8] = {dq0.x, dq0.y, dq0.z, dq0.w, dq1.x, dq1.y, dq1.z, dq1.w};
#pragma unroll
      for (int i = 0; i < 8; ++i) {
        w1v[i].x = fmaf(da[i], kR0.x, w1v[i].x);
        w1v[i].y = fmaf(da[i], kR0.y, w1v[i].y);
      }
      float tp[8];
#pragma unroll
      for (int i = 0; i < 8; ++i) tp[i] = fmaf(w1v[i].x, xv.x, w1v[i].y * xv.y);
      float zA = allred4(tp[0], tp[1], tp[2], tp[3]);
      float zB = allred4(tp[4], tp[5], tp[6], tp[7]);
      if (rowlead) {
        tp1[sig] = zA;
        tp1[4 + sig] = zB;
      }
    }
    __syncthreads();  // X_2047
  }
}

extern "C" void kernel_launch(void* const* d_in, const int* in_sizes, int n_in,
                              void* d_out, int out_size, void* d_ws, size_t ws_size,
                              hipStream_t stream) {
  const float* h  = (const float*)d_in[0];
  const float* W1 = (const float*)d_in[1];
  const float* b1 = (const float*)d_in[2];
  const float* W2 = (const float*)d_in[3];
  const float* b2 = (const float*)d_in[4];
  float* out = (float*)d_out;
  ttt_kernel<<<256, 128, 0, stream>>>(h, W1, b1, W2, b2, out);
}